// Round 1
// baseline (174.586 us; speedup 1.0000x reference)
//
#include <hip/hip_runtime.h>
#include <cmath>

#define KK 16
#define HID 256
#define NROWH 30720   // P*BS = 120*256
#define NROW 61440
#define GM 4096       // BS*K
#define GK 512        // FT
#define GN 512        // 2*HID
#define EPSV 1e-5f
#define SLOPEV 0.01f
#define NSTAT 240     // stats partial blocks

// ---------------- K1: UV = X(4096x512) @ [W1_top | W1_bot](512x512), +b1 on cols<256
__global__ __launch_bounds__(256) void k_gemm(const float* __restrict__ X,
                                              const float* __restrict__ W1,
                                              const float* __restrict__ b1,
                                              float* __restrict__ UV) {
  __shared__ float As[16][68];   // row stride 68 floats = 272B (16B aligned), 2-way bank conflict on write (free)
  __shared__ float Bs[16][64];
  const int m0 = (blockIdx.x >> 3) * 64;   // 64 m-tiles
  const int n0 = (blockIdx.x & 7) * 64;    // 8 n-tiles
  const int t  = threadIdx.x;
  const int ty = t >> 4, tx = t & 15;
  float acc[4][4] = {};
  for (int k0 = 0; k0 < GK; k0 += 16) {
    #pragma unroll
    for (int u = 0; u < 4; u++) {
      int e = t + 256 * u;            // 0..1023
      int m = e >> 4, k = e & 15;     // 64x16 A tile
      As[k][m] = X[(m0 + m) * GK + k0 + k];
    }
    #pragma unroll
    for (int u = 0; u < 4; u++) {
      int e = t + 256 * u;
      int r = e >> 6, c = e & 63;     // 16x64 B tile
      int d = k0 + r, nn = n0 + c;
      Bs[r][c] = (nn < HID) ? W1[d * HID + nn]
                            : W1[d * HID + (nn - HID) + GK * HID];
    }
    __syncthreads();
    #pragma unroll
    for (int kk = 0; kk < 16; kk++) {
      float4 av = *reinterpret_cast<const float4*>(&As[kk][ty * 4]);
      float4 bv = *reinterpret_cast<const float4*>(&Bs[kk][tx * 4]);
      float a[4] = {av.x, av.y, av.z, av.w};
      float b[4] = {bv.x, bv.y, bv.z, bv.w};
      #pragma unroll
      for (int i = 0; i < 4; i++)
        #pragma unroll
        for (int j = 0; j < 4; j++)
          acc[i][j] = fmaf(a[i], b[j], acc[i][j]);
    }
    __syncthreads();
  }
  #pragma unroll
  for (int i = 0; i < 4; i++) {
    int m = m0 + ty * 4 + i;
    #pragma unroll
    for (int j = 0; j < 4; j++) {
      int nn = n0 + tx * 4 + j;
      float add = (nn < HID) ? b1[nn] : 0.0f;
      UV[m * GN + nn] = acc[i][j] + add;
    }
  }
}

__device__ __forceinline__ void decode_pair(int p, int& iu, int& ju) {
  int i = 0, q = p;
  while (q >= 15 - i) { q -= 15 - i; i++; }
  iu = i; ju = i + 1 + q;
}

// ---------------- K2: per-feature partial sums of h and h^2 over all 61440 virtual rows
__global__ __launch_bounds__(256) void k_stats(const float* __restrict__ UV,
                                               float* __restrict__ partial) {
  const int blk = blockIdx.x;           // 240
  const int p = blk >> 1;
  const int b0 = (blk & 1) * 128;
  const int f = threadIdx.x;            // feature 0..255
  int iu, ju; decode_pair(p, iu, ju);
  float s1 = 0.f, s2 = 0.f;
  for (int b = b0; b < b0 + 128; b++) {
    const int bi  = (b * KK + iu) * GN;
    const int bj1 = (b * KK + ju) * GN + HID;
    const int bj2 = (((b - p - 1) & 255) * KK + ju) * GN + HID;
    float u  = UV[bi + f];
    float h1 = u + UV[bj1 + f];
    float h2 = u + UV[bj2 + f];
    s1 += h1 + h2;
    s2 += h1 * h1 + h2 * h2;
  }
  partial[blk * 512 + f]       = s1;
  partial[blk * 512 + 256 + f] = s2;
}

// ---------------- K3: reduce partials -> per-feature affine a,c; zero loss acc
__global__ __launch_bounds__(512) void k_finalize(const float* __restrict__ partial,
                                                  const float* __restrict__ gamma,
                                                  const float* __restrict__ beta,
                                                  float* __restrict__ af,
                                                  float* __restrict__ cf,
                                                  float* __restrict__ lossAcc) {
  __shared__ float S[512];
  const int t = threadIdx.x;
  float s = 0.f;
  for (int blk = 0; blk < NSTAT; blk++) s += partial[blk * 512 + t];
  S[t] = s;
  __syncthreads();
  if (t < 256) {
    float mean = S[t] * (1.0f / NROW);
    float var  = S[t + 256] * (1.0f / NROW) - mean * mean;
    float a = gamma[t] * rsqrtf(var + EPSV);
    af[t] = a;
    cf[t] = beta[t] - mean * a;
  }
  if (t == 0) *lossAcc = 0.f;
}

// ---------------- K4: one wave per (p,b) item -> pos & neg scores
__global__ __launch_bounds__(256) void k_scores(const float* __restrict__ UV,
                                                const float* __restrict__ af,
                                                const float* __restrict__ cf,
                                                const float* __restrict__ W2,
                                                const float* __restrict__ b2,
                                                float* __restrict__ out) {
  const int wv = blockIdx.x * 4 + (threadIdx.x >> 6);   // 0..30719 == p*256+b
  const int lane = threadIdx.x & 63;
  const int p = wv >> 8, b = wv & 255;
  int iu, ju; decode_pair(p, iu, ju);
  const int bi  = (b * KK + iu) * GN;
  const int bj1 = (b * KK + ju) * GN + HID;
  const int bj2 = (((b - p - 1) & 255) * KK + ju) * GN + HID;
  float sp = 0.f, sn = 0.f;
  #pragma unroll
  for (int r = 0; r < 4; r++) {
    int f = lane + r * 64;
    float u = UV[bi + f];
    float a = af[f], c = cf[f], w = W2[f];
    float h1 = fmaf(a, u + UV[bj1 + f], c);
    h1 = h1 >= 0.f ? h1 : SLOPEV * h1;
    sp = fmaf(w, h1, sp);
    float h2 = fmaf(a, u + UV[bj2 + f], c);
    h2 = h2 >= 0.f ? h2 : SLOPEV * h2;
    sn = fmaf(w, h2, sn);
  }
  #pragma unroll
  for (int off = 32; off > 0; off >>= 1) {
    sp += __shfl_xor(sp, off, 64);
    sn += __shfl_xor(sn, off, 64);
  }
  if (lane == 0) {
    float bb = b2[0];
    out[1 + wv]         = sp + bb;
    out[1 + NROWH + wv] = sn + bb;
  }
}

// ---------------- K5: correct bits (coalesced) + BCE partial
__global__ __launch_bounds__(256) void k_bce(float* __restrict__ out,
                                             float* __restrict__ lossAcc) {
  const int row = blockIdx.x * 256 + threadIdx.x;   // 240*256 = 61440
  float s = out[1 + row];
  const bool tgt = row < NROWH;
  float bce = fmaxf(s, 0.f) - (tgt ? s : 0.f) + log1pf(expf(-fabsf(s)));
  #pragma unroll
  for (int tt = 1; tt <= 9; tt++) {
    bool pred = (double)s > (double)tt / 10.0;   // match numpy float64 scalar promotion
    out[1 + NROW + (tt - 1) * NROW + row] = (pred == tgt) ? 1.0f : 0.0f;
  }
  #pragma unroll
  for (int off = 32; off > 0; off >>= 1) bce += __shfl_xor(bce, off, 64);
  __shared__ float wsum[4];
  const int lane = threadIdx.x & 63, w = threadIdx.x >> 6;
  if (lane == 0) wsum[w] = bce;
  __syncthreads();
  if (threadIdx.x == 0) atomicAdd(lossAcc, wsum[0] + wsum[1] + wsum[2] + wsum[3]);
}

// ---------------- K6: final loss
__global__ void k_loss(const float* __restrict__ lossAcc, float* __restrict__ out) {
  if (threadIdx.x == 0) out[0] = *lossAcc * (1.0f / NROW);
}

extern "C" void kernel_launch(void* const* d_in, const int* in_sizes, int n_in,
                              void* d_out, int out_size, void* d_ws, size_t ws_size,
                              hipStream_t stream) {
  const float* X     = (const float*)d_in[0];  // cnn_output (256,16,512) == (4096,512)
  const float* W1    = (const float*)d_in[1];  // (1024,256)
  const float* b1    = (const float*)d_in[2];
  const float* gamma = (const float*)d_in[3];
  const float* beta  = (const float*)d_in[4];
  const float* W2    = (const float*)d_in[5];  // (256,1)
  const float* b2    = (const float*)d_in[6];
  float* out = (float*)d_out;

  float* UV      = (float*)d_ws;                 // 4096*512
  float* partial = UV + GM * GN;                 // NSTAT*512
  float* af      = partial + NSTAT * 512;        // 256
  float* cf      = af + 256;                     // 256
  float* lossAcc = cf + 256;                     // 1

  hipLaunchKernelGGL(k_gemm,     dim3(512),  dim3(256), 0, stream, X, W1, b1, UV);
  hipLaunchKernelGGL(k_stats,    dim3(NSTAT),dim3(256), 0, stream, UV, partial);
  hipLaunchKernelGGL(k_finalize, dim3(1),    dim3(512), 0, stream, partial, gamma, beta, af, cf, lossAcc);
  hipLaunchKernelGGL(k_scores,   dim3(7680), dim3(256), 0, stream, UV, af, cf, W2, b2, out);
  hipLaunchKernelGGL(k_bce,      dim3(240),  dim3(256), 0, stream, out, lossAcc);
  hipLaunchKernelGGL(k_loss,     dim3(1),    dim3(64),  0, stream, lossAcc, out);
}

// Round 4
// 171.463 us; speedup vs baseline: 1.0182x; 1.0182x over previous
//
#include <hip/hip_runtime.h>
#include <cmath>

#define KK 16
#define HID 256
#define NROWH 30720   // P*BS = 120*256
#define NROW 61440
#define GM 4096       // BS*K
#define GK 512        // FT
#define GN 512        // 2*HID
#define EPSV 1e-5f
#define SLOPEV 0.01f

#define BM 128
#define BN 64
#define BK 16
#define NT 16         // K-iters per split (256/16)

// ---------------- K0: UV = b1 broadcast pattern; zero sums8 + lossAcc
__global__ __launch_bounds__(256) void k_init(const float* __restrict__ b1,
                                              float* __restrict__ UV,
                                              float* __restrict__ sums8) {
  const int idx = blockIdx.x * 256 + threadIdx.x;   // 8192*256 = 2M
  const int n = idx & (GN - 1);
  UV[idx] = (n < HID) ? b1[n] : 0.0f;
  if (idx <= 8 * 512) sums8[idx] = 0.0f;            // sums8[4096] + lossAcc
}

// ---------------- K1: UV += X(4096x512) @ [W1_top | W1_bot](512x512)
// split-K=2, double-buffered LDS, 1 barrier/iter, 8x4 per thread
__global__ __launch_bounds__(256) void k_gemm(const float* __restrict__ X,
                                              const float* __restrict__ W1,
                                              float* __restrict__ UV) {
  __shared__ float As[2][BK][BM + 4];   // k-major, padded
  __shared__ float Bs[2][BK][BN];
  const int bid = blockIdx.x;
  const int ks  = bid & 1;              // K split
  const int tb  = bid >> 1;             // 0..255
  const int m0  = (tb >> 3) * BM;
  const int n0  = (tb & 7) * BN;
  const float* Wb = (n0 < HID) ? (W1 + n0) : (W1 + GK * HID + (n0 - HID));
  const int kbase = ks * (GK / 2);
  const int t = threadIdx.x;
  // staging indices
  const int am = t >> 2;                // 0..63 (A row pair)
  const int aq = t & 3;                 // A k-quad
  const int brr = t >> 4;               // 0..15 (B k row)
  const int bq  = t & 15;               // B n-quad
  // compute indices
  const int ty = t >> 4;                // m frag = ty*8
  const int tx = t & 15;                // n frag = tx*4

  const float* Xp = X + (size_t)m0 * GK + kbase;

  float4 ar0, ar1, br0;
  float acc[8][4] = {};

  auto stage = [&](int it) {
    const float* Xq = Xp + it * BK;
    ar0 = *(const float4*)(Xq + am * GK + aq * 4);
    ar1 = *(const float4*)(Xq + (am + 64) * GK + aq * 4);
    br0 = *(const float4*)(Wb + (size_t)(kbase + it * BK + brr) * HID + bq * 4);
  };
  auto write_lds = [&](int buf) {
    As[buf][aq * 4 + 0][am] = ar0.x;
    As[buf][aq * 4 + 1][am] = ar0.y;
    As[buf][aq * 4 + 2][am] = ar0.z;
    As[buf][aq * 4 + 3][am] = ar0.w;
    As[buf][aq * 4 + 0][am + 64] = ar1.x;
    As[buf][aq * 4 + 1][am + 64] = ar1.y;
    As[buf][aq * 4 + 2][am + 64] = ar1.z;
    As[buf][aq * 4 + 3][am + 64] = ar1.w;
    *(float4*)&Bs[buf][brr][bq * 4] = br0;
  };

  stage(0);
  write_lds(0);
  __syncthreads();
  for (int it = 0; it < NT; ++it) {
    if (it + 1 < NT) stage(it + 1);           // global loads hidden under compute
    const int buf = it & 1;
    #pragma unroll
    for (int kk = 0; kk < BK; ++kk) {
      float4 a0 = *(const float4*)&As[buf][kk][ty * 8];
      float4 a1 = *(const float4*)&As[buf][kk][ty * 8 + 4];
      float4 b  = *(const float4*)&Bs[buf][kk][tx * 4];
      float av[8] = {a0.x, a0.y, a0.z, a0.w, a1.x, a1.y, a1.z, a1.w};
      float bv[4] = {b.x, b.y, b.z, b.w};
      #pragma unroll
      for (int i = 0; i < 8; i++)
        #pragma unroll
        for (int j = 0; j < 4; j++)
          acc[i][j] = fmaf(av[i], bv[j], acc[i][j]);
    }
    if (it + 1 < NT) write_lds((it + 1) & 1); // waits vmcnt here, not at barrier top
    __syncthreads();
  }
  #pragma unroll
  for (int i = 0; i < 8; i++) {
    const int m = m0 + ty * 8 + i;
    #pragma unroll
    for (int j = 0; j < 4; j++)
      atomicAdd(&UV[(size_t)m * GN + n0 + tx * 4 + j], acc[i][j]);
  }
}

__device__ __forceinline__ void decode_pair(int p, int& iu, int& ju) {
  int i = 0, q = p;
  while (q >= 15 - i) { q -= 15 - i; i++; }
  iu = i; ju = i + 1 + q;
}

// ---------------- K2: per-feature sums of h, h^2 over 61440 virtual rows
// 960 blocks -> atomicAdd into 8 contention-spread copies
__global__ __launch_bounds__(256) void k_stats(const float* __restrict__ UV,
                                               float* __restrict__ sums8) {
  const int blk = blockIdx.x;           // 0..959
  const int p = blk >> 3;
  const int b0 = (blk & 7) * 32;
  const int f = threadIdx.x;            // feature 0..255
  int iu, ju; decode_pair(p, iu, ju);
  float s1 = 0.f, s2 = 0.f;
  for (int b = b0; b < b0 + 32; b++) {
    const int bi  = (b * KK + iu) * GN;
    const int bj1 = (b * KK + ju) * GN + HID;
    const int bj2 = (((b - p - 1) & 255) * KK + ju) * GN + HID;
    float u  = UV[bi + f];
    float h1 = u + UV[bj1 + f];
    float h2 = u + UV[bj2 + f];
    s1 += h1 + h2;
    s2 += h1 * h1 + h2 * h2;
  }
  float* dst = sums8 + (blk & 7) * 512;
  atomicAdd(dst + f, s1);
  atomicAdd(dst + 256 + f, s2);
}

// ---------------- K3: reduce 8 copies -> per-feature affine a,c
__global__ __launch_bounds__(256) void k_finalize(const float* __restrict__ sums8,
                                                  const float* __restrict__ gamma,
                                                  const float* __restrict__ beta,
                                                  float* __restrict__ af,
                                                  float* __restrict__ cf) {
  const int f = threadIdx.x;
  float s1 = 0.f, s2 = 0.f;
  #pragma unroll
  for (int c = 0; c < 8; c++) {
    s1 += sums8[c * 512 + f];
    s2 += sums8[c * 512 + 256 + f];
  }
  float mean = s1 * (1.0f / NROW);
  float var  = s2 * (1.0f / NROW) - mean * mean;
  float a = gamma[f] * rsqrtf(var + EPSV);
  af[f] = a;
  cf[f] = beta[f] - mean * a;
}

// ---------------- K4: one wave per (p,b) item -> pos & neg scores
__global__ __launch_bounds__(256) void k_scores(const float* __restrict__ UV,
                                                const float* __restrict__ af,
                                                const float* __restrict__ cf,
                                                const float* __restrict__ W2,
                                                const float* __restrict__ b2,
                                                float* __restrict__ out) {
  const int wv = blockIdx.x * 4 + (threadIdx.x >> 6);   // 0..30719 == p*256+b
  const int lane = threadIdx.x & 63;
  const int p = wv >> 8, b = wv & 255;
  int iu, ju; decode_pair(p, iu, ju);
  const int bi  = (b * KK + iu) * GN;
  const int bj1 = (b * KK + ju) * GN + HID;
  const int bj2 = (((b - p - 1) & 255) * KK + ju) * GN + HID;
  float sp = 0.f, sn = 0.f;
  #pragma unroll
  for (int r = 0; r < 4; r++) {
    int f = lane + r * 64;
    float u = UV[bi + f];
    float a = af[f], c = cf[f], w = W2[f];
    float h1 = fmaf(a, u + UV[bj1 + f], c);
    h1 = h1 >= 0.f ? h1 : SLOPEV * h1;
    sp = fmaf(w, h1, sp);
    float h2 = fmaf(a, u + UV[bj2 + f], c);
    h2 = h2 >= 0.f ? h2 : SLOPEV * h2;
    sn = fmaf(w, h2, sn);
  }
  #pragma unroll
  for (int off = 32; off > 0; off >>= 1) {
    sp += __shfl_xor(sp, off, 64);
    sn += __shfl_xor(sn, off, 64);
  }
  if (lane == 0) {
    float bb = b2[0];
    out[1 + wv]         = sp + bb;
    out[1 + NROWH + wv] = sn + bb;
  }
}

// ---------------- K5: correct bits (coalesced) + BCE partial
__global__ __launch_bounds__(256) void k_bce(float* __restrict__ out,
                                             float* __restrict__ lossAcc) {
  const int row = blockIdx.x * 256 + threadIdx.x;   // 240*256 = 61440
  float s = out[1 + row];
  const bool tgt = row < NROWH;
  float bce = fmaxf(s, 0.f) - (tgt ? s : 0.f) + log1pf(expf(-fabsf(s)));
  #pragma unroll
  for (int tt = 1; tt <= 9; tt++) {
    bool pred = (double)s > (double)tt / 10.0;   // match numpy float64 scalar promotion
    out[1 + NROW + (tt - 1) * NROW + row] = (pred == tgt) ? 1.0f : 0.0f;
  }
  #pragma unroll
  for (int off = 32; off > 0; off >>= 1) bce += __shfl_xor(bce, off, 64);
  __shared__ float wsum[4];
  const int lane = threadIdx.x & 63, w = threadIdx.x >> 6;
  if (lane == 0) wsum[w] = bce;
  __syncthreads();
  if (threadIdx.x == 0) atomicAdd(lossAcc, wsum[0] + wsum[1] + wsum[2] + wsum[3]);
}

// ---------------- K6: final loss
__global__ void k_loss(const float* __restrict__ lossAcc, float* __restrict__ out) {
  if (threadIdx.x == 0) out[0] = *lossAcc * (1.0f / NROW);
}

extern "C" void kernel_launch(void* const* d_in, const int* in_sizes, int n_in,
                              void* d_out, int out_size, void* d_ws, size_t ws_size,
                              hipStream_t stream) {
  const float* X     = (const float*)d_in[0];  // cnn_output (256,16,512) == (4096,512)
  const float* W1    = (const float*)d_in[1];  // (1024,256)
  const float* b1    = (const float*)d_in[2];
  const float* gamma = (const float*)d_in[3];
  const float* beta  = (const float*)d_in[4];
  const float* W2    = (const float*)d_in[5];  // (256,1)
  const float* b2    = (const float*)d_in[6];
  float* out = (float*)d_out;

  float* UV      = (float*)d_ws;                 // 4096*512
  float* sums8   = UV + (size_t)GM * GN;         // 8*512
  float* lossAcc = sums8 + 8 * 512;              // 1
  float* af      = lossAcc + 1;                  // 256
  float* cf      = af + 256;                     // 256

  hipLaunchKernelGGL(k_init,     dim3(8192), dim3(256), 0, stream, b1, UV, sums8);
  hipLaunchKernelGGL(k_gemm,     dim3(512),  dim3(256), 0, stream, X, W1, UV);
  hipLaunchKernelGGL(k_stats,    dim3(960),  dim3(256), 0, stream, UV, sums8);
  hipLaunchKernelGGL(k_finalize, dim3(1),    dim3(256), 0, stream, sums8, gamma, beta, af, cf);
  hipLaunchKernelGGL(k_scores,   dim3(7680), dim3(256), 0, stream, UV, af, cf, W2, b2, out);
  hipLaunchKernelGGL(k_bce,      dim3(240),  dim3(256), 0, stream, out, lossAcc);
  hipLaunchKernelGGL(k_loss,     dim3(1),    dim3(64),  0, stream, lossAcc, out);
}

// Round 8
// 142.104 us; speedup vs baseline: 1.2286x; 1.2066x over previous
//
#include <hip/hip_runtime.h>
#include <cmath>

#define KK 16
#define HID 256
#define NROWH 30720   // P*BS = 120*256
#define NROW 61440
#define GM 4096       // BS*K
#define GK 512        // FT
#define GN 512        // 2*HID
#define EPSV 1e-5f
#define SLOPEV 0.01f

#define BM 64
#define BN 32
#define BK 16
#define NT 32         // K iterations (512/16), no split-K

// ---------------- K1: UV = X(4096x512) @ [W1_top | W1_bot](512x512) + b1-pattern
// grid 1024 (4 blocks/CU), 4x2 per thread, double-buffered LDS, no atomics
__global__ __launch_bounds__(256) void k_gemm(const float* __restrict__ X,
                                              const float* __restrict__ W1,
                                              const float* __restrict__ b1,
                                              float* __restrict__ UV,
                                              float* __restrict__ sums8) {
  // block 0 zeros the stats accumulators + lossAcc (consumed only after this kernel)
  if (blockIdx.x == 0) {
    for (int i = threadIdx.x; i < 8 * 512 + 1; i += 256) sums8[i] = 0.0f;
  }
  __shared__ float As[2][BK][BM];   // k-major
  __shared__ float Bs[2][BK][BN];
  // XCD swizzle: 8 consecutive M-panels per XCD (X panel 1MB + W1 1MB -> L2-resident)
  const int id  = blockIdx.x;            // 0..1023
  const int xcd = id & 7, wi = id >> 3;  // wi 0..127
  const int mt  = xcd * 8 + (wi >> 4);   // 0..63
  const int nt  = wi & 15;               // 0..15
  const int m0  = mt * BM, n0 = nt * BN;
  const float* Wb = (n0 < HID) ? (W1 + n0) : (W1 + GK * HID + (n0 - HID));
  const int t = threadIdx.x;
  // staging indices
  const int arow = t >> 2;               // 0..63
  const int akq  = t & 3;                // k-quad
  const int brow = t >> 3;               // 0..31 (only t<128 stages B)
  const int bcq  = t & 7;                // n-quad
  // compute indices
  const int ty = t >> 4;                 // 0..15 -> m frag ty*4
  const int tx = t & 15;                 // 0..15 -> n frag tx*2

  const float* Xp = X + (size_t)m0 * GK;

  float4 ar, br;
  float acc[4][2] = {};

  auto stage = [&](int it) {
    ar = *(const float4*)(Xp + (size_t)arow * GK + it * BK + akq * 4);
    if (t < 128)
      br = *(const float4*)(Wb + (size_t)(it * BK + brow) * HID + bcq * 4);
  };
  auto write_lds = [&](int buf) {
    As[buf][akq * 4 + 0][arow] = ar.x;
    As[buf][akq * 4 + 1][arow] = ar.y;
    As[buf][akq * 4 + 2][arow] = ar.z;
    As[buf][akq * 4 + 3][arow] = ar.w;
    if (t < 128) *(float4*)&Bs[buf][brow][bcq * 4] = br;
  };

  stage(0);
  write_lds(0);
  __syncthreads();
  for (int it = 0; it < NT; ++it) {
    if (it + 1 < NT) stage(it + 1);            // global loads in flight under compute
    const int buf = it & 1;
    #pragma unroll
    for (int kk = 0; kk < BK; ++kk) {
      float4 a = *(const float4*)&As[buf][kk][ty * 4];
      float2 b = *(const float2*)&Bs[buf][kk][tx * 2];
      float av[4] = {a.x, a.y, a.z, a.w};
      float bv[2] = {b.x, b.y};
      #pragma unroll
      for (int i = 0; i < 4; i++)
        #pragma unroll
        for (int j = 0; j < 2; j++)
          acc[i][j] = fmaf(av[i], bv[j], acc[i][j]);
    }
    if (it + 1 < NT) write_lds((it + 1) & 1);  // vmcnt wait lands here
    __syncthreads();
  }
  const int n = n0 + tx * 2;
  const float add0 = (n < HID) ? b1[n] : 0.0f;
  const float add1 = (n + 1 < HID) ? b1[n + 1] : 0.0f;
  #pragma unroll
  for (int i = 0; i < 4; i++) {
    const int m = m0 + ty * 4 + i;
    float2 v = {acc[i][0] + add0, acc[i][1] + add1};
    *(float2*)&UV[(size_t)m * GN + n] = v;
  }
}

__device__ __forceinline__ void decode_pair(int p, int& iu, int& ju) {
  int i = 0, q = p;
  while (q >= 15 - i) { q -= 15 - i; i++; }
  iu = i; ju = i + 1 + q;
}

// ---------------- K2: per-feature sums of h, h^2 over 61440 virtual rows
// 960 blocks (XCD-swizzled) -> atomicAdd into 8 contention-spread copies
__global__ __launch_bounds__(256) void k_stats(const float* __restrict__ UV,
                                               float* __restrict__ sums8) {
  const int bid = blockIdx.x;                    // 0..959
  const int blk = (bid & 7) * 120 + (bid >> 3);  // same-p blocks share an XCD
  const int p = blk >> 3;
  const int b0 = (blk & 7) * 32;
  const int f = threadIdx.x;                     // feature 0..255
  int iu, ju; decode_pair(p, iu, ju);
  float s1 = 0.f, s2 = 0.f;
  for (int b = b0; b < b0 + 32; b++) {
    const int bi  = (b * KK + iu) * GN;
    const int bj1 = (b * KK + ju) * GN + HID;
    const int bj2 = (((b - p - 1) & 255) * KK + ju) * GN + HID;
    float u  = UV[bi + f];
    float h1 = u + UV[bj1 + f];
    float h2 = u + UV[bj2 + f];
    s1 += h1 + h2;
    s2 += h1 * h1 + h2 * h2;
  }
  float* dst = sums8 + (bid & 7) * 512;
  atomicAdd(dst + f, s1);
  atomicAdd(dst + 256 + f, s2);
}

// ---------------- K3: reduce 8 copies -> per-feature affine a,c
__global__ __launch_bounds__(256) void k_finalize(const float* __restrict__ sums8,
                                                  const float* __restrict__ gamma,
                                                  const float* __restrict__ beta,
                                                  float* __restrict__ af,
                                                  float* __restrict__ cf) {
  const int f = threadIdx.x;
  float s1 = 0.f, s2 = 0.f;
  #pragma unroll
  for (int c = 0; c < 8; c++) {
    s1 += sums8[c * 512 + f];
    s2 += sums8[c * 512 + 256 + f];
  }
  float mean = s1 * (1.0f / NROW);
  float var  = s2 * (1.0f / NROW) - mean * mean;
  float a = gamma[f] * rsqrtf(var + EPSV);
  af[f] = a;
  cf[f] = beta[f] - mean * a;
}

// ---------------- K4: one wave per (p,b) item -> pos & neg scores
__global__ __launch_bounds__(256) void k_scores(const float* __restrict__ UV,
                                                const float* __restrict__ af,
                                                const float* __restrict__ cf,
                                                const float* __restrict__ W2,
                                                const float* __restrict__ b2,
                                                float* __restrict__ out) {
  const int bid = blockIdx.x;                    // 0..7679
  const int swz = (bid & 7) * 960 + (bid >> 3);  // same-p blocks share an XCD
  const int wv = swz * 4 + (threadIdx.x >> 6);   // 0..30719 == p*256+b
  const int lane = threadIdx.x & 63;
  const int p = wv >> 8, b = wv & 255;
  int iu, ju; decode_pair(p, iu, ju);
  const int bi  = (b * KK + iu) * GN;
  const int bj1 = (b * KK + ju) * GN + HID;
  const int bj2 = (((b - p - 1) & 255) * KK + ju) * GN + HID;
  float sp = 0.f, sn = 0.f;
  #pragma unroll
  for (int r = 0; r < 4; r++) {
    int f = lane + r * 64;
    float u = UV[bi + f];
    float a = af[f], c = cf[f], w = W2[f];
    float h1 = fmaf(a, u + UV[bj1 + f], c);
    h1 = h1 >= 0.f ? h1 : SLOPEV * h1;
    sp = fmaf(w, h1, sp);
    float h2 = fmaf(a, u + UV[bj2 + f], c);
    h2 = h2 >= 0.f ? h2 : SLOPEV * h2;
    sn = fmaf(w, h2, sn);
  }
  #pragma unroll
  for (int off = 32; off > 0; off >>= 1) {
    sp += __shfl_xor(sp, off, 64);
    sn += __shfl_xor(sn, off, 64);
  }
  if (lane == 0) {
    float bb = b2[0];
    out[1 + wv]         = sp + bb;
    out[1 + NROWH + wv] = sn + bb;
  }
}

// ---------------- K5: correct bits (coalesced) + BCE partial
__global__ __launch_bounds__(256) void k_bce(float* __restrict__ out,
                                             float* __restrict__ lossAcc) {
  const int row = blockIdx.x * 256 + threadIdx.x;   // 240*256 = 61440
  float s = out[1 + row];
  const bool tgt = row < NROWH;
  float bce = fmaxf(s, 0.f) - (tgt ? s : 0.f) + log1pf(expf(-fabsf(s)));
  #pragma unroll
  for (int tt = 1; tt <= 9; tt++) {
    bool pred = (double)s > (double)tt / 10.0;   // match numpy float64 scalar promotion
    out[1 + NROW + (tt - 1) * NROW + row] = (pred == tgt) ? 1.0f : 0.0f;
  }
  #pragma unroll
  for (int off = 32; off > 0; off >>= 1) bce += __shfl_xor(bce, off, 64);
  __shared__ float wsum[4];
  const int lane = threadIdx.x & 63, w = threadIdx.x >> 6;
  if (lane == 0) wsum[w] = bce;
  __syncthreads();
  if (threadIdx.x == 0) atomicAdd(lossAcc, wsum[0] + wsum[1] + wsum[2] + wsum[3]);
}

// ---------------- K6: final loss
__global__ void k_loss(const float* __restrict__ lossAcc, float* __restrict__ out) {
  if (threadIdx.x == 0) out[0] = *lossAcc * (1.0f / NROW);
}

extern "C" void kernel_launch(void* const* d_in, const int* in_sizes, int n_in,
                              void* d_out, int out_size, void* d_ws, size_t ws_size,
                              hipStream_t stream) {
  const float* X     = (const float*)d_in[0];  // cnn_output (256,16,512) == (4096,512)
  const float* W1    = (const float*)d_in[1];  // (1024,256)
  const float* b1    = (const float*)d_in[2];
  const float* gamma = (const float*)d_in[3];
  const float* beta  = (const float*)d_in[4];
  const float* W2    = (const float*)d_in[5];  // (256,1)
  const float* b2    = (const float*)d_in[6];
  float* out = (float*)d_out;

  float* UV      = (float*)d_ws;                 // 4096*512
  float* sums8   = UV + (size_t)GM * GN;         // 8*512
  float* lossAcc = sums8 + 8 * 512;              // 1
  float* af      = lossAcc + 1;                  // 256
  float* cf      = af + 256;                     // 256

  hipLaunchKernelGGL(k_gemm,     dim3(1024), dim3(256), 0, stream, X, W1, b1, UV, sums8);
  hipLaunchKernelGGL(k_stats,    dim3(960),  dim3(256), 0, stream, UV, sums8);
  hipLaunchKernelGGL(k_finalize, dim3(1),    dim3(256), 0, stream, sums8, gamma, beta, af, cf);
  hipLaunchKernelGGL(k_scores,   dim3(7680), dim3(256), 0, stream, UV, af, cf, W2, b2, out);
  hipLaunchKernelGGL(k_bce,      dim3(240),  dim3(256), 0, stream, out, lossAcc);
  hipLaunchKernelGGL(k_loss,     dim3(1),    dim3(64),  0, stream, lossAcc, out);
}

// Round 10
// 131.900 us; speedup vs baseline: 1.3236x; 1.0774x over previous
//
#include <hip/hip_runtime.h>
#include <cmath>

#define KK 16
#define HID 256
#define NROWH 30720   // P*BS = 120*256
#define NROW 61440
#define GM 4096       // BS*K
#define GK 512        // FT
#define GN 512        // 2*HID
#define EPSV 1e-5f
#define SLOPEV 0.01f

#define BM 128
#define BN 64
#define BK 16
#define NT 32         // K iterations (512/16)

// ---------------- K1: UV = X(4096x512) @ [W1_top | W1_bot](512x512) + b1
// grid 256 (1 block/CU), 8x4 per thread (0.67 FMA/LDS-byte), double-buffered LDS
__global__ __launch_bounds__(256) void k_gemm(const float* __restrict__ X,
                                              const float* __restrict__ W1,
                                              const float* __restrict__ b1,
                                              float* __restrict__ UV,
                                              float* __restrict__ zbuf) {
  // block 0 zeros sums8(4096) + lossAcc64(1024) — consumed only by later kernels
  if (blockIdx.x == 0) {
    for (int i = threadIdx.x; i < 5120; i += 256) zbuf[i] = 0.0f;
  }
  __shared__ float As[2][BK][BM];   // k-major: As[k][m]
  __shared__ float Bs[2][BK][BN];
  const int id = blockIdx.x;        // 0..255
  const int nt = id >> 5;           // 0..7
  const int mt = id & 31;           // 0..31; same-mt blocks have id≡mt (mod 8) -> same XCD
  const int m0 = mt * BM, n0 = nt * BN;
  const float* Wb = (n0 < HID) ? (W1 + n0) : (W1 + GK * HID + (n0 - HID));
  const int t = threadIdx.x;
  // A staging: thread (am = t&127, half = t>>7) loads A[m0+am][it*16 + half*8 .. +8]
  const int am  = t & 127;
  const int ak8 = (t >> 7) * 8;     // 0 or 8
  // B staging: (brr = t>>4, bq = t&15) loads one float4
  const int brr = t >> 4, bq = t & 15;
  // compute: m-frag ty*8, n-frag tx*4
  const int ty = t >> 4, tx = t & 15;

  const float* Xp = X + (size_t)(m0 + am) * GK;

  float4 a40, a41, b4;
  float acc[8][4] = {};

  auto stage = [&](int it) {
    const int k0 = it * BK + ak8;
    a40 = *(const float4*)(Xp + k0);
    a41 = *(const float4*)(Xp + k0 + 4);
    b4  = *(const float4*)(Wb + (size_t)(it * BK + brr) * HID + bq * 4);
  };
  auto wr = [&](int buf) {
    As[buf][ak8 + 0][am] = a40.x;
    As[buf][ak8 + 1][am] = a40.y;
    As[buf][ak8 + 2][am] = a40.z;
    As[buf][ak8 + 3][am] = a40.w;
    As[buf][ak8 + 4][am] = a41.x;
    As[buf][ak8 + 5][am] = a41.y;
    As[buf][ak8 + 6][am] = a41.z;
    As[buf][ak8 + 7][am] = a41.w;
    *(float4*)&Bs[buf][brr][bq * 4] = b4;
  };

  stage(0);
  wr(0);
  __syncthreads();
  for (int it = 0; it < NT; ++it) {
    if (it + 1 < NT) stage(it + 1);            // next-tile global loads in flight
    const int buf = it & 1;
    #pragma unroll
    for (int kk = 0; kk < BK; ++kk) {
      float4 x0 = *(const float4*)&As[buf][kk][ty * 8];
      float4 x1 = *(const float4*)&As[buf][kk][ty * 8 + 4];
      float4 y  = *(const float4*)&Bs[buf][kk][tx * 4];
      float av[8] = {x0.x, x0.y, x0.z, x0.w, x1.x, x1.y, x1.z, x1.w};
      float bv[4] = {y.x, y.y, y.z, y.w};
      #pragma unroll
      for (int i = 0; i < 8; i++)
        #pragma unroll
        for (int j = 0; j < 4; j++)
          acc[i][j] = fmaf(av[i], bv[j], acc[i][j]);
    }
    if (it + 1 < NT) wr((it + 1) & 1);         // vmcnt wait lands here
    __syncthreads();
  }
  const int n = n0 + tx * 4;
  float4 add = {0.f, 0.f, 0.f, 0.f};
  if (n < HID) add = *(const float4*)&b1[n];
  #pragma unroll
  for (int i = 0; i < 8; i++) {
    const int m = m0 + ty * 8 + i;
    float4 v = {acc[i][0] + add.x, acc[i][1] + add.y, acc[i][2] + add.z, acc[i][3] + add.w};
    *(float4*)&UV[(size_t)m * GN + n] = v;
  }
}

__device__ __forceinline__ void decode_pair(int p, int& iu, int& ju) {
  int i = 0, q = p;
  while (q >= 15 - i) { q -= 15 - i; i++; }
  iu = i; ju = i + 1 + q;
}

// ---------------- K2: per-feature sums of h, h^2 over 61440 virtual rows
__global__ __launch_bounds__(256) void k_stats(const float* __restrict__ UV,
                                               float* __restrict__ sums8) {
  const int bid = blockIdx.x;                    // 0..959
  const int blk = (bid & 7) * 120 + (bid >> 3);  // same-p blocks share an XCD
  const int p = blk >> 3;
  const int b0 = (blk & 7) * 32;
  const int f = threadIdx.x;                     // feature 0..255
  int iu, ju; decode_pair(p, iu, ju);
  float s1 = 0.f, s2 = 0.f;
  for (int b = b0; b < b0 + 32; b++) {
    const int bi  = (b * KK + iu) * GN;
    const int bj1 = (b * KK + ju) * GN + HID;
    const int bj2 = (((b - p - 1) & 255) * KK + ju) * GN + HID;
    float u  = UV[bi + f];
    float h1 = u + UV[bj1 + f];
    float h2 = u + UV[bj2 + f];
    s1 += h1 + h2;
    s2 += h1 * h1 + h2 * h2;
  }
  float* dst = sums8 + (bid & 7) * 512;
  atomicAdd(dst + f, s1);
  atomicAdd(dst + 256 + f, s2);
}

// ---------------- K3: reduce 8 copies -> per-feature affine a,c
__global__ __launch_bounds__(256) void k_finalize(const float* __restrict__ sums8,
                                                  const float* __restrict__ gamma,
                                                  const float* __restrict__ beta,
                                                  float* __restrict__ af,
                                                  float* __restrict__ cf) {
  const int f = threadIdx.x;
  float s1 = 0.f, s2 = 0.f;
  #pragma unroll
  for (int c = 0; c < 8; c++) {
    s1 += sums8[c * 512 + f];
    s2 += sums8[c * 512 + 256 + f];
  }
  float mean = s1 * (1.0f / NROW);
  float var  = s2 * (1.0f / NROW) - mean * mean;
  float a = gamma[f] * rsqrtf(var + EPSV);
  af[f] = a;
  cf[f] = beta[f] - mean * a;
}

// ---------------- K4: scores + correct bits + BCE partials (fused)
__global__ __launch_bounds__(256) void k_scores(const float* __restrict__ UV,
                                                const float* __restrict__ af,
                                                const float* __restrict__ cf,
                                                const float* __restrict__ W2,
                                                const float* __restrict__ b2,
                                                float* __restrict__ out,
                                                float* __restrict__ lossAcc64) {
  const int bid = blockIdx.x;                    // 0..7679
  const int swz = (bid & 7) * 960 + (bid >> 3);  // same-p blocks share an XCD
  const int wv0 = swz * 4;
  const int w = threadIdx.x >> 6;
  const int lane = threadIdx.x & 63;
  const int wv = wv0 + w;
  const int p = wv >> 8, b = wv & 255;
  int iu, ju; decode_pair(p, iu, ju);
  const int bi  = (b * KK + iu) * GN;
  const int bj1 = (b * KK + ju) * GN + HID;
  const int bj2 = (((b - p - 1) & 255) * KK + ju) * GN + HID;
  float sp = 0.f, sn = 0.f;
  #pragma unroll
  for (int r = 0; r < 4; r++) {
    int f = lane + r * 64;
    float u = UV[bi + f];
    float a = af[f], c = cf[f], ww = W2[f];
    float h1 = fmaf(a, u + UV[bj1 + f], c);
    h1 = h1 >= 0.f ? h1 : SLOPEV * h1;
    sp = fmaf(ww, h1, sp);
    float h2 = fmaf(a, u + UV[bj2 + f], c);
    h2 = h2 >= 0.f ? h2 : SLOPEV * h2;
    sn = fmaf(ww, h2, sn);
  }
  #pragma unroll
  for (int off = 32; off > 0; off >>= 1) {
    sp += __shfl_xor(sp, off, 64);
    sn += __shfl_xor(sn, off, 64);
  }
  __shared__ float sc[8];
  __shared__ float sbce[8];
  if (lane == 0) {
    float bb = b2[0];
    sc[w]     = sp + bb;
    sc[4 + w] = sn + bb;
  }
  __syncthreads();
  const int t = threadIdx.x;
  if (t < 8) {
    const int j = t & 3;
    const bool pos = t < 4;
    const int row = (pos ? 0 : NROWH) + wv0 + j;
    const float s = sc[t];
    out[1 + row] = s;
    float bce = fmaxf(s, 0.f) - (pos ? s : 0.f) + log1pf(expf(-fabsf(s)));
    sbce[t] = bce;
    #pragma unroll
    for (int tt = 1; tt <= 9; tt++) {
      bool pred = (double)s > (double)tt / 10.0;   // match numpy float64 promotion
      out[1 + NROW + (tt - 1) * NROW + row] = (pred == pos) ? 1.0f : 0.0f;
    }
  }
  __syncthreads();
  if (t == 0) {
    float bsum = sbce[0] + sbce[1] + sbce[2] + sbce[3]
               + sbce[4] + sbce[5] + sbce[6] + sbce[7];
    atomicAdd(&lossAcc64[(bid & 63) * 16], bsum);   // 64 line-spread slots
  }
}

// ---------------- K5: final loss from 64 spread slots
__global__ void k_loss(const float* __restrict__ lossAcc64, float* __restrict__ out) {
  const int t = threadIdx.x;           // 64 threads
  float v = lossAcc64[t * 16];
  #pragma unroll
  for (int off = 32; off > 0; off >>= 1) v += __shfl_xor(v, off, 64);
  if (t == 0) out[0] = v * (1.0f / NROW);
}

extern "C" void kernel_launch(void* const* d_in, const int* in_sizes, int n_in,
                              void* d_out, int out_size, void* d_ws, size_t ws_size,
                              hipStream_t stream) {
  const float* X     = (const float*)d_in[0];  // cnn_output (256,16,512) == (4096,512)
  const float* W1    = (const float*)d_in[1];  // (1024,256)
  const float* b1    = (const float*)d_in[2];
  const float* gamma = (const float*)d_in[3];
  const float* beta  = (const float*)d_in[4];
  const float* W2    = (const float*)d_in[5];  // (256,1)
  const float* b2    = (const float*)d_in[6];
  float* out = (float*)d_out;

  float* UV        = (float*)d_ws;               // 4096*512
  float* sums8     = UV + (size_t)GM * GN;       // 4096 floats
  float* lossAcc64 = sums8 + 8 * 512;            // 64 slots * 16 floats
  float* af        = lossAcc64 + 1024;           // 256
  float* cf        = af + 256;                   // 256

  hipLaunchKernelGGL(k_gemm,     dim3(256),  dim3(256), 0, stream, X, W1, b1, UV, sums8);
  hipLaunchKernelGGL(k_stats,    dim3(960),  dim3(256), 0, stream, UV, sums8);
  hipLaunchKernelGGL(k_finalize, dim3(1),    dim3(256), 0, stream, sums8, gamma, beta, af, cf);
  hipLaunchKernelGGL(k_scores,   dim3(7680), dim3(256), 0, stream, UV, af, cf, W2, b2, out, lossAcc64);
  hipLaunchKernelGGL(k_loss,     dim3(1),    dim3(64),  0, stream, lossAcc64, out);
}